// Round 1
// baseline (367.427 us; speedup 1.0000x reference)
//
#include <hip/hip_runtime.h>

typedef _Float16 half_t;
typedef __attribute__((ext_vector_type(8))) _Float16 half8;
typedef __attribute__((ext_vector_type(4))) float f32x4;

#define NB 32
#define NH 128
#define NW 128
#define NOH 122
#define NOW 122
#define NOC 512
#define NTAP 49
#define KPAD 64

// ws layout (bytes):
//   gh: [32][128][128] half  @ 0         (1048576)
//   Wh: [512][64]      half  @ 1048576   (65536)
//   w2: [512]          float @ 1114112   (2048)
//   x2: [32][122][122] float @ 1116160   (1905152)
// total ~3.0 MB

__global__ __launch_bounds__(256) void k_gray(const float* __restrict__ x,
                                              half_t* __restrict__ gh) {
    int t = blockIdx.x * 256 + threadIdx.x;
    if (t >= NB * NH * NW) return;
    int b = t >> 14;
    int pix = t & 16383;
    const float* xb = x + (size_t)b * 3 * 16384;
    float g = 0.2989f * xb[pix] + 0.587f * xb[16384 + pix] + 0.114f * xb[32768 + pix];
    gh[t] = (half_t)g;
}

__global__ __launch_bounds__(64) void k_w(const float* __restrict__ w,
                                          half_t* __restrict__ Wh,
                                          float* __restrict__ w2) {
    int o = blockIdx.x * 64 + threadIdx.x;
    if (o >= NOC) return;
    float s = 0.f;
    for (int t = 0; t < KPAD; ++t) {
        float v = (t < NTAP) ? w[o * NTAP + t] : 0.f;
        half_t h = (half_t)v;
        Wh[o * KPAD + t] = h;
        float f = (float)h;
        s += f * f;
    }
    w2[o] = s;
}

__global__ __launch_bounds__(256) void k_x2(const half_t* __restrict__ gh,
                                            float* __restrict__ x2) {
    int t = blockIdx.x * 256 + threadIdx.x;
    if (t >= NB * NOH * NOW) return;
    int b = t / (NOH * NOW);
    int rem = t - b * (NOH * NOW);
    int oh = rem / NOW;
    int ow = rem - oh * NOW;
    const half_t* g = gh + ((size_t)b * NH + oh) * NW + ow;
    float s = 0.f;
#pragma unroll
    for (int kh = 0; kh < 7; ++kh) {
#pragma unroll
        for (int kw = 0; kw < 7; ++kw) {
            float v = (float)g[kh * NW + kw];
            s += v * v;
        }
    }
    x2[t] = s;
}

__global__ __launch_bounds__(256) void k_main(const half_t* __restrict__ gh,
                                              const half_t* __restrict__ Wh,
                                              const float* __restrict__ w2,
                                              const float* __restrict__ x2,
                                              const float* __restrict__ stdp,
                                              float* __restrict__ out) {
    const int fg = blockIdx.x;   // 0..7  (group of 64 filters)
    const int oh = blockIdx.y;   // 0..121
    const int b  = blockIdx.z;   // 0..31

    __shared__ half_t gS[10][136];  // rows 7..9 and cols 128..135 zeroed (K-pad)

    const int tid = threadIdx.x;
    for (int idx = tid; idx < 10 * 136; idx += 256) {
        int r = idx / 136;
        int c = idx - r * 136;
        half_t hv = (half_t)0.f;
        if (r < 7 && c < 128) hv = gh[((size_t)b * NH + (oh + r)) * NW + c];
        gS[r][c] = hv;
    }

    const int wave = tid >> 6;
    const int lane = tid & 63;
    const int col  = lane & 15;
    const int kq   = lane >> 4;
    const int n0   = wave * 32;

    // A fragments: A[row=filter (lane&15)][k=(lane>>4)*8+i], contiguous half8 in Wh
    half8 afrag[4][2];
#pragma unroll
    for (int mi = 0; mi < 4; ++mi) {
#pragma unroll
        for (int ks = 0; ks < 2; ++ks) {
            const half_t* ap = Wh + ((size_t)(fg * 64 + mi * 16 + col) * KPAD + ks * 32 + kq * 8);
            afrag[mi][ks] = *(const half8*)ap;
        }
    }

    __syncthreads();

    // B fragments: B[k][col=position], k = ks*32 + kq*8 + i, tap -> (kh,kw)
    half8 bfrag[2][2];
#pragma unroll
    for (int ni = 0; ni < 2; ++ni) {
#pragma unroll
        for (int ks = 0; ks < 2; ++ks) {
            half8 v;
#pragma unroll
            for (int i = 0; i < 8; ++i) {
                int t = ks * 32 + kq * 8 + i;
                int kh = (t * 37) >> 8;     // t/7 for t<64
                int kw = t - kh * 7;
                v[i] = gS[kh][n0 + ni * 16 + col + kw];
            }
            bfrag[ni][ks] = v;
        }
    }

    f32x4 acc[4][2];
#pragma unroll
    for (int mi = 0; mi < 4; ++mi)
#pragma unroll
        for (int ni = 0; ni < 2; ++ni) {
            f32x4 z = {0.f, 0.f, 0.f, 0.f};
            acc[mi][ni] = z;
        }

#pragma unroll
    for (int ks = 0; ks < 2; ++ks)
#pragma unroll
        for (int mi = 0; mi < 4; ++mi)
#pragma unroll
            for (int ni = 0; ni < 2; ++ni)
                acc[mi][ni] = __builtin_amdgcn_mfma_f32_16x16x32_f16(
                    afrag[mi][ks], bfrag[ni][ks], acc[mi][ni], 0, 0, 0);

    const float sv = stdp[0];
    const float inv2s2 = 0.5f / (sv * sv);

#pragma unroll
    for (int ni = 0; ni < 2; ++ni) {
        const int p = n0 + ni * 16 + col;
        const bool pok = p < NOW;
        const float x2v = pok ? x2[((size_t)b * NOH + oh) * NOW + p] : 0.f;
#pragma unroll
        for (int mi = 0; mi < 4; ++mi) {
#pragma unroll
            for (int r = 0; r < 4; ++r) {
                const int o = fg * 64 + mi * 16 + kq * 4 + r;  // D: row=(lane>>4)*4+r
                float sq = x2v + w2[o] - 2.f * acc[mi][ni][r];
                sq = fmaxf(sq, 0.f);
                float res = __expf(-sq * inv2s2);
                if (pok) out[(((size_t)b * NOC + o) * NOH + oh) * NOW + p] = res;
            }
        }
    }
}

extern "C" void kernel_launch(void* const* d_in, const int* in_sizes, int n_in,
                              void* d_out, int out_size, void* d_ws, size_t ws_size,
                              hipStream_t stream) {
    const float* x    = (const float*)d_in[0];
    const float* w    = (const float*)d_in[1];
    const float* stdp = (const float*)d_in[2];
    float* out = (float*)d_out;

    char* ws = (char*)d_ws;
    half_t* gh = (half_t*)ws;
    half_t* Wh = (half_t*)(ws + 1048576);
    float*  w2 = (float*)(ws + 1114112);
    float*  x2 = (float*)(ws + 1116160);

    k_gray<<<(NB * NH * NW + 255) / 256, 256, 0, stream>>>(x, gh);
    k_w<<<(NOC + 63) / 64, 64, 0, stream>>>(w, Wh, w2);
    k_x2<<<(NB * NOH * NOW + 255) / 256, 256, 0, stream>>>(gh, x2);

    dim3 grid(8, NOH, NB);
    k_main<<<grid, 256, 0, stream>>>(gh, Wh, w2, x2, stdp, out);
}